// Round 3
// baseline (5438.132 us; speedup 1.0000x reference)
//
#include <hip/hip_runtime.h>
#include <cstdint>

#define Bb 64
#define Tt 4096
#define Dd 67
#define Hh 128

typedef _Float16 f16;
typedef _Float16 half8 __attribute__((ext_vector_type(8)));
typedef float f32x4 __attribute__((ext_vector_type(4)));

#define MFMA16(A,B,C) __builtin_amdgcn_mfma_f32_16x16x32_f16((A),(B),(C),0,0,0)

static __device__ __forceinline__ float fast_rcp(float x){ return __builtin_amdgcn_rcpf(x); }
static __device__ __forceinline__ float fast_ex2(float x){ return __builtin_amdgcn_exp2f(x); }
#define L2E  1.442695041f
#define L2E2 2.885390082f

union U2 { uint2 u; f16 h[4]; };
union U1 { unsigned u; f16 h[2]; };

__device__ __forceinline__ void red2(float& s, float& q){
#pragma unroll
  for (int off = 32; off; off >>= 1){ s += __shfl_xor(s, off); q += __shfl_xor(q, off); }
}

// LDS-visibility barrier WITHOUT vmcnt drain (T3/T4): global loads stay in
// flight across it; "memory" clobber pins LDS/global op ordering.
#define SYNC() asm volatile("s_waitcnt lgkmcnt(0)\ns_barrier" ::: "memory")

// ---------------------------------------------------------------------------
// Stage A: LN(67) -> MFMA proj -> LN(128)+SiLU -> MFMA GEMM2 -> z fp16 to
// d_ws in layout [b][t][512], zoff(j,g) = (j>>5)*128+(j&15)*8+((j>>4)&1)*4+g.
// (unchanged, verified)
// ---------------------------------------------------------------------------
__global__ __launch_bounds__(512, 2)
void stage_a(const float* __restrict__ x,
             const float* __restrict__ g_in, const float* __restrict__ b_in,
             const float* __restrict__ proj_w, const float* __restrict__ proj_b,
             const float* __restrict__ g_p, const float* __restrict__ b_p,
             const float* __restrict__ w_ff1, const float* __restrict__ bi_ff1,
             const float* __restrict__ w_ff2, const float* __restrict__ bi_ff2,
             const float* __restrict__ w_ta,  const float* __restrict__ bi_ta,
             const float* __restrict__ w_tb,  const float* __restrict__ bi_tb,
             f16* __restrict__ zx)
{
  __shared__ __align__(16) f16   xn_s[16*104];
  __shared__ __align__(16) float fpre_s[16*132];
  __shared__ __align__(16) f16   feat_s[16*136];

  const int tid  = threadIdx.x;
  const int wv   = tid >> 6;
  const int lane = tid & 63;
  const int q    = lane >> 4;
  const int l16  = lane & 15;
  const int jq   = 16*wv + 4*q;

  const float* Wg[4] = { w_ff1, w_ff2, w_ta, w_tb };
  const float* Bg[4] = { bi_ff1, bi_ff2, bi_ta, bi_tb };

  half8 aW1[3];
#pragma unroll
  for (int c = 0; c < 3; ++c)
#pragma unroll
    for (int i = 0; i < 8; ++i){
      int k = 32*c + 8*q + i;
      aW1[c][i] = (k < Dd) ? (f16)proj_w[k*Hh + (16*wv + l16)] : (f16)0.f;
    }
  half8 aW2[4][4];
  f32x4 bias2[4];
#pragma unroll
  for (int g = 0; g < 4; ++g){
    const float* wp = Wg[g];
    const int jc = 16*wv + l16;
#pragma unroll
    for (int c = 0; c < 4; ++c)
#pragma unroll
      for (int i = 0; i < 8; ++i){
        int k = 32*c + 8*q + i;
        aW2[g][c][i] = (f16)wp[k*Hh + jc];
      }
    bias2[g] = *(const f32x4*)(Bg[g] + jq);
  }
  const float gi0 = g_in[lane], bi0 = b_in[lane];
  const float gi1 = (lane < 3) ? g_in[64+lane] : 0.f;
  const float bi1 = (lane < 3) ? b_in[64+lane] : 0.f;
  const float gp0 = g_p[lane],  bp0 = b_p[lane];
  const float gp1 = g_p[64+lane], bp1 = b_p[64+lane];
  const float pb0 = proj_b[lane], pb1 = proj_b[64+lane];

  for (int idx = tid; idx < 16*104; idx += 512)
    if ((idx % 104) >= Dd) xn_s[idx] = (f16)0.f;
  __syncthreads();

  const int wg   = blockIdx.x;
  const int b    = wg >> 2;
  const int t0wg = (wg & 3) * 1024;

  for (int it = 0; it < 64; ++it){
    const int tl0 = t0wg + it*16;
#pragma unroll
    for (int hf = 0; hf < 2; ++hf){
      const int ts = wv + 8*hf;
      const float* xr = x + (size_t)(b*Tt + tl0 + ts) * Dd;
      float v0 = xr[lane];
      float v1 = (lane < 3) ? xr[64+lane] : 0.f;
      float s = v0 + v1, qq = v0*v0 + v1*v1;
      red2(s, qq);
      float mu = s * (1.0f/Dd);
      float rstd = rsqrtf(qq * (1.0f/Dd) - mu*mu + 1e-5f);
      xn_s[ts*104 + lane] = (f16)((v0 - mu)*rstd*gi0 + bi0);
      if (lane < 3) xn_s[ts*104 + 64 + lane] = (f16)((v1 - mu)*rstd*gi1 + bi1);
    }
    __syncthreads();
    {
      f32x4 acc = {0.f, 0.f, 0.f, 0.f};
#pragma unroll
      for (int c = 0; c < 3; ++c){
        half8 bf = *(const half8*)(xn_s + l16*104 + 32*c + 8*q);
        acc = MFMA16(aW1[c], bf, acc);
      }
      *(f32x4*)(fpre_s + l16*132 + jq) = acc;
    }
    __syncthreads();
#pragma unroll
    for (int hf = 0; hf < 2; ++hf){
      const int ts = wv + 8*hf;
      float v0 = fpre_s[ts*132 + lane]      + pb0;
      float v1 = fpre_s[ts*132 + 64 + lane] + pb1;
      float s = v0 + v1, qq = v0*v0 + v1*v1;
      red2(s, qq);
      float mu = s * (1.0f/Hh);
      float rstd = rsqrtf(qq * (1.0f/Hh) - mu*mu + 1e-5f);
      float f0 = (v0 - mu)*rstd*gp0 + bp0;
      float f1 = (v1 - mu)*rstd*gp1 + bp1;
      f0 *= fast_rcp(1.0f + fast_ex2(-L2E*f0));
      f1 *= fast_rcp(1.0f + fast_ex2(-L2E*f1));
      feat_s[ts*136 + lane]      = (f16)f0;
      feat_s[ts*136 + 64 + lane] = (f16)f1;
    }
    __syncthreads();
    {
      half8 bf2[4];
#pragma unroll
      for (int c = 0; c < 4; ++c)
        bf2[c] = *(const half8*)(feat_s + l16*136 + 32*c + 8*q);
      const size_t trow = (size_t)(b*Tt + tl0 + l16) * 512;
      f32x4 accs2[4];
#pragma unroll
      for (int g = 0; g < 4; ++g){
        f32x4 acc = bias2[g];
#pragma unroll
        for (int c = 0; c < 4; ++c)
          acc = MFMA16(aW2[g][c], bf2[c], acc);
        accs2[g] = acc;
      }
#pragma unroll
      for (int r = 0; r < 4; ++r){
        U2 u;
#pragma unroll
        for (int g = 0; g < 4; ++g) u.h[g] = (f16)accs2[g][r];
        const int zoff = ((wv>>1)*128) + ((4*q + r)*8) + ((wv&1)*4);
        *(uint2*)(zx + trow + zoff) = u.u;
      }
    }
    __syncthreads();
  }
}

// ---------------------------------------------------------------------------
// Scan v9: v8 structure (4 blocks x 512 thr, M=16 batches packed) with the
// drain surgery: (1) lgkm-only barriers (global loads fly across), (2) 4-step
// chunked z/dt register prefetch, ping-pong, issued one chunk ahead, (3)
// 8-step superloop so all LDS ring offsets are compile-time immediates.
// ---------------------------------------------------------------------------
#define ISSUE_Z(ZBUF, TBASE)                                                   \
  {                                                                            \
    _Pragma("unroll")                                                          \
    for (int st = 0; st < 4; ++st){                                            \
      const int tc = ((TBASE)+st < Tt) ? (TBASE)+st : Tt-1;                    \
      const size_t tt = (size_t)tc * 512;                                      \
      _Pragma("unroll")                                                        \
      for (int r = 0; r < 4; ++r)                                              \
        ZBUF[st][r] = *(const uint2*)(zx + zb[r] + tt);                        \
    }                                                                          \
  }

#define ISSUE_D(DBUF, TBASE)                                                   \
  {                                                                            \
    const int tc = ((TBASE) + 4 <= Tt) ? (TBASE) : Tt-4;                       \
    _Pragma("unroll")                                                          \
    for (int r = 0; r < 4; ++r)                                                \
      DBUF[r] = *(const float4*)(dtp[r] + tc);                                 \
  }

// J: literal 0..7 (t8 = 0 mod 8 -> ring slots are literals)
#define STEP(J, ZS, DB)                                                        \
  {                                                                            \
    half8 af[4];                                                               \
    _Pragma("unroll")                                                          \
    for (int cc = 0; cc < 4; ++cc)                                             \
      af[cc] = *(const half8*)(hbase + ((((J)+7)&7)*4096 + afo[cc]));          \
    U2 uz0, uz1, uz2, uz3;                                                     \
    uz0.u = ZS[0]; uz1.u = ZS[1]; uz2.u = ZS[2]; uz3.u = ZS[3];                \
    f32x4 acc[4];                                                              \
    _Pragma("unroll")                                                          \
    for (int g = 0; g < 4; ++g){                                               \
      acc[g][0] = (float)uz0.h[g]; acc[g][1] = (float)uz1.h[g];                \
      acc[g][2] = (float)uz2.h[g]; acc[g][3] = (float)uz3.h[g];                \
    }                                                                          \
    _Pragma("unroll")                                                          \
    for (int cc = 0; cc < 4; ++cc){                                            \
      acc[0] = MFMA16(af[cc], bW[0][cc], acc[0]);                              \
      acc[1] = MFMA16(af[cc], bW[1][cc], acc[1]);                              \
      acc[2] = MFMA16(af[cc], bW[2][cc], acc[2]);                              \
      acc[3] = MFMA16(af[cc], bW[3][cc], acc[3]);                              \
    }                                                                          \
    _Pragma("unroll")                                                          \
    for (int r = 0; r < 4; ++r){                                               \
      float dtt = DB[r][(J)&3] * 10.0f;                                        \
      float gpre = __builtin_fmaf(acc[2][r], dtt, acc[3][r]);                  \
      float g_ = fast_rcp(fast_ex2(-L2E*gpre) + 1.0f);                         \
      float u_ = fast_rcp(fast_ex2(L2E2*acc[0][r]) + 1.0f);                    \
      float v_ = fast_rcp(fast_ex2(L2E2*acc[1][r]) + 1.0f);                    \
      float a_ = __builtin_fmaf(-2.0f, u_, 1.0f);                              \
      float hn = __builtin_fmaf(2.0f*g_, u_ - v_, a_);                         \
      *(f16*)(hbase + (((J)&7)*4096 + hwo[r])) = (f16)hn;                      \
    }                                                                          \
    SYNC();                                                                    \
  }

__global__ __launch_bounds__(512, 1)
void scan_k(f16* __restrict__ zx, const float* __restrict__ dt,
            const float* __restrict__ w_ff1, const float* __restrict__ w_ff2,
            const float* __restrict__ w_ta,  const float* __restrict__ w_tb)
{
  __shared__ __align__(16) f16 hist[8][2048];   // 8 slots x [b(16) x 128j] swizzled = 32 KB

  const int tid  = threadIdx.x;
  const int w8   = tid >> 6;
  const int lane = tid & 63;
  const int q    = lane >> 4;
  const int l16  = lane & 15;
  const int sb   = blockIdx.x;                  // 0..3

  const float* Wg[4] = { w_ff1, w_ff2, w_ta, w_tb };

  // B operand: n-col j = 16*w8 + l16, k-rows 128+32cc+8q+i (h-half of cat)
  half8 bW[4][4];
#pragma unroll
  for (int g = 0; g < 4; ++g){
    const float* wp = Wg[g];
    const int jc = 16*w8 + l16;
#pragma unroll
    for (int c = 0; c < 4; ++c)
#pragma unroll
      for (int i = 0; i < 8; ++i)
        bW[g][c][i] = (f16)wp[(128 + 32*c + 8*q + i)*Hh + jc];
  }

  // zero hist ring (slot 7 = h(-1) must be 0)
#pragma unroll
  for (int k = 0; k < 4; ++k)
    ((float4*)&hist[0][0])[k*512 + tid] = make_float4(0.f,0.f,0.f,0.f);

  // per-lane z slot: zoff(j,g)=(j>>5)*128+(j&15)*8+((j>>4)&1)*4+g
  const int zoff = (w8>>1)*128 + l16*8 + (w8&1)*4;
  size_t zb[4];
  const float* dtp[4];
#pragma unroll
  for (int r = 0; r < 4; ++r){
    const int bg = sb*16 + 4*q + r;
    zb[r]  = (size_t)bg * Tt * 512 + zoff;
    dtp[r] = dt + (size_t)bg * Tt;
  }

  // constant per-lane LDS byte offsets (XOR swizzle: byte ^= (b&7)<<4 in row)
  const char* hbase = (const char*)&hist[0][0];
  int afo[4];   // read: h[b=l16][k=32cc+8q+i], b128
#pragma unroll
  for (int cc = 0; cc < 4; ++cc)
    afo[cc] = l16*256 + ((64*cc + 16*q) ^ ((l16&7)<<4));
  int hwo[4];   // write: h[b=4q+r][j=16w8+l16], b16
#pragma unroll
  for (int r = 0; r < 4; ++r)
    hwo[r] = (4*q+r)*256 + ((2*(16*w8+l16)) ^ (((4*q+r)&7)<<4));

  __syncthreads();   // hist zero visible; one-time full drain is fine here

  // prologue: chunk {0..3} -> zA, chunk {4..7} -> zB (both in flight)
  uint2 zA[4][4], zB[4][4];
  float4 dbufA[4], dbufB[4];
  ISSUE_Z(zA, 0); ISSUE_D(dbufA, 0);
  ISSUE_Z(zB, 4); ISSUE_D(dbufB, 4);

  for (int t8 = 0; t8 < Tt; t8 += 8){
    STEP(0, zA[0], dbufA) STEP(1, zA[1], dbufA)
    STEP(2, zA[2], dbufA) STEP(3, zA[3], dbufA)
    ISSUE_Z(zA, t8+8);  ISSUE_D(dbufA, t8+8);
    STEP(4, zB[0], dbufB) STEP(5, zB[1], dbufB)
    STEP(6, zB[2], dbufB) STEP(7, zB[3], dbufB)
    ISSUE_Z(zB, t8+12); ISSUE_D(dbufB, t8+12);
    // dump h(t8..t8+7) into consumed z region: h[t] -> zg[t*512 + 0..127]
    {
      const int db = lane >> 2;
      const int jb = (lane & 3) * 32;
      f16* gdst = zx + (size_t)(sb*16+db)*Tt*512 + (size_t)(t8+w8)*512 + jb;
#pragma unroll
      for (int k2 = 0; k2 < 4; ++k2){
        half8 hv = *(const half8*)(hbase + w8*4096 + db*256
                                   + ((jb*2 + 16*k2) ^ ((db&7)<<4)));
        *(half8*)(gdst + 8*k2) = hv;
      }
    }
    SYNC();
  }
}

// ---------------------------------------------------------------------------
// Head: out[tok] = h[tok] . head_w + head_b (h fp16 from dumped region).
// ---------------------------------------------------------------------------
__global__ __launch_bounds__(256, 4)
void head_k(const f16* __restrict__ zx, const float* __restrict__ head_w,
            const float* __restrict__ head_b, float* __restrict__ out)
{
  const int tok  = (blockIdx.x << 2) + (threadIdx.x >> 6);
  const int lane = threadIdx.x & 63;
  U1 cv; cv.u = *(const unsigned*)(zx + (size_t)tok*512 + 2*lane);
  float s = (float)cv.h[0]*head_w[2*lane] + (float)cv.h[1]*head_w[2*lane+1];
#pragma unroll
  for (int off = 32; off; off >>= 1) s += __shfl_xor(s, off);
  if (lane == 0) out[tok] = s + head_b[0];
}

extern "C" void kernel_launch(void* const* d_in, const int* in_sizes, int n_in,
                              void* d_out, int out_size, void* d_ws, size_t ws_size,
                              hipStream_t stream)
{
  const float* x       = (const float*)d_in[0];
  const float* dt      = (const float*)d_in[1];
  const float* ln_in_g = (const float*)d_in[2];
  const float* ln_in_b = (const float*)d_in[3];
  const float* proj_w  = (const float*)d_in[4];
  const float* proj_b  = (const float*)d_in[5];
  const float* ln_p_g  = (const float*)d_in[6];
  const float* ln_p_b  = (const float*)d_in[7];
  const float* ff1_w   = (const float*)d_in[8];
  const float* ff1_b   = (const float*)d_in[9];
  const float* ff2_w   = (const float*)d_in[10];
  const float* ff2_b   = (const float*)d_in[11];
  const float* ta_w    = (const float*)d_in[12];
  const float* ta_b    = (const float*)d_in[13];
  const float* tb_w    = (const float*)d_in[14];
  const float* tb_b    = (const float*)d_in[15];
  const float* head_w  = (const float*)d_in[16];
  const float* head_b  = (const float*)d_in[17];

  f16*   zx  = (f16*)d_ws;      // [b][t][512] fp16 = 256 MiB (z, then h)
  float* out = (float*)d_out;

  stage_a<<<dim3(256), dim3(512), 0, stream>>>(
      x, ln_in_g, ln_in_b, proj_w, proj_b, ln_p_g, ln_p_b,
      ff1_w, ff1_b, ff2_w, ff2_b, ta_w, ta_b, tb_w, tb_b, zx);

  scan_k<<<dim3(4), dim3(512), 0, stream>>>(
      zx, dt, ff1_w, ff2_w, ta_w, tb_w);

  head_k<<<dim3(Bb*Tt/4), dim3(256), 0, stream>>>(
      zx, head_w, head_b, out);
}

// Round 5
// 2834.853 us; speedup vs baseline: 1.9183x; 1.9183x over previous
//
#include <hip/hip_runtime.h>
#include <cstdint>

#define Bb 64
#define Tt 4096
#define Dd 67
#define Hh 128
#define CH 16            // scan z-chunk: 16 steps x 512 n x 2B = 16 KB
#define NCH (Tt/CH)

typedef _Float16 f16;
typedef _Float16 half8 __attribute__((ext_vector_type(8)));
typedef float f32x4 __attribute__((ext_vector_type(4)));

#define MFMA16(A,B,C) __builtin_amdgcn_mfma_f32_16x16x32_f16((A),(B),(C),0,0,0)

static __device__ __forceinline__ float fast_rcp(float x){ return __builtin_amdgcn_rcpf(x); }
static __device__ __forceinline__ float fast_ex2(float x){ return __builtin_amdgcn_exp2f(x); }
static __device__ __forceinline__ float rlane(float v, int l){
  return __builtin_bit_cast(float, __builtin_amdgcn_readlane(__builtin_bit_cast(int, v), l));
}
#define L2E  1.442695041f
#define L2E2 2.885390082f

// LDS-visibility barrier WITHOUT vmcnt drain: global loads/stores stay in
// flight across it. "memory" clobber pins LDS op ordering at compile time;
// barrier builtin keeps convergence semantics.
#define SYNC() do { asm volatile("s_waitcnt lgkmcnt(0)" ::: "memory"); \
                    __builtin_amdgcn_s_barrier(); } while(0)

union U2 { uint2 u; f16 h[4]; };
union U1 { unsigned u; f16 h[2]; };

__device__ __forceinline__ void red2(float& s, float& q){
#pragma unroll
  for (int off = 32; off; off >>= 1){ s += __shfl_xor(s, off); q += __shfl_xor(q, off); }
}

// ---------------------------------------------------------------------------
// Stage A: LN(67) -> MFMA proj -> LN(128)+SiLU -> MFMA GEMM2 -> z fp16 to
// d_ws in scan layout [b][t][w(4)][l16(16)][(s,g)(8)]  (1 b128/lane in scan).
// (unchanged, verified)
// ---------------------------------------------------------------------------
__global__ __launch_bounds__(512, 2)
void stage_a(const float* __restrict__ x,
             const float* __restrict__ g_in, const float* __restrict__ b_in,
             const float* __restrict__ proj_w, const float* __restrict__ proj_b,
             const float* __restrict__ g_p, const float* __restrict__ b_p,
             const float* __restrict__ w_ff1, const float* __restrict__ bi_ff1,
             const float* __restrict__ w_ff2, const float* __restrict__ bi_ff2,
             const float* __restrict__ w_ta,  const float* __restrict__ bi_ta,
             const float* __restrict__ w_tb,  const float* __restrict__ bi_tb,
             f16* __restrict__ zx)
{
  __shared__ __align__(16) f16   xn_s[16*104];
  __shared__ __align__(16) float fpre_s[16*132];
  __shared__ __align__(16) f16   feat_s[16*136];

  const int tid  = threadIdx.x;
  const int wv   = tid >> 6;
  const int lane = tid & 63;
  const int q    = lane >> 4;
  const int l16  = lane & 15;
  const int jq   = 16*wv + 4*q;

  const float* Wg[4] = { w_ff1, w_ff2, w_ta, w_tb };
  const float* Bg[4] = { bi_ff1, bi_ff2, bi_ta, bi_tb };

  half8 aW1[3];
#pragma unroll
  for (int c = 0; c < 3; ++c)
#pragma unroll
    for (int i = 0; i < 8; ++i){
      int k = 32*c + 8*q + i;
      aW1[c][i] = (k < Dd) ? (f16)proj_w[k*Hh + (16*wv + l16)] : (f16)0.f;
    }
  half8 aW2[4][4];
  f32x4 bias2[4];
#pragma unroll
  for (int g = 0; g < 4; ++g){
    const float* wp = Wg[g];
    const int jc = 16*wv + l16;
#pragma unroll
    for (int c = 0; c < 4; ++c)
#pragma unroll
      for (int i = 0; i < 8; ++i){
        int k = 32*c + 8*q + i;
        aW2[g][c][i] = (f16)wp[k*Hh + jc];
      }
    bias2[g] = *(const f32x4*)(Bg[g] + jq);
  }
  const float gi0 = g_in[lane], bi0 = b_in[lane];
  const float gi1 = (lane < 3) ? g_in[64+lane] : 0.f;
  const float bi1 = (lane < 3) ? b_in[64+lane] : 0.f;
  const float gp0 = g_p[lane],  bp0 = b_p[lane];
  const float gp1 = g_p[64+lane], bp1 = b_p[64+lane];
  const float pb0 = proj_b[lane], pb1 = proj_b[64+lane];

  for (int idx = tid; idx < 16*104; idx += 512)
    if ((idx % 104) >= Dd) xn_s[idx] = (f16)0.f;
  __syncthreads();

  const int wg   = blockIdx.x;
  const int b    = wg >> 2;
  const int t0wg = (wg & 3) * 1024;

  for (int it = 0; it < 64; ++it){
    const int tl0 = t0wg + it*16;
#pragma unroll
    for (int hf = 0; hf < 2; ++hf){
      const int ts = wv + 8*hf;
      const float* xr = x + (size_t)(b*Tt + tl0 + ts) * Dd;
      float v0 = xr[lane];
      float v1 = (lane < 3) ? xr[64+lane] : 0.f;
      float s = v0 + v1, qq = v0*v0 + v1*v1;
      red2(s, qq);
      float mu = s * (1.0f/Dd);
      float rstd = rsqrtf(qq * (1.0f/Dd) - mu*mu + 1e-5f);
      xn_s[ts*104 + lane] = (f16)((v0 - mu)*rstd*gi0 + bi0);
      if (lane < 3) xn_s[ts*104 + 64 + lane] = (f16)((v1 - mu)*rstd*gi1 + bi1);
    }
    __syncthreads();
    {
      f32x4 acc = {0.f, 0.f, 0.f, 0.f};
#pragma unroll
      for (int c = 0; c < 3; ++c){
        half8 bf = *(const half8*)(xn_s + l16*104 + 32*c + 8*q);
        acc = MFMA16(aW1[c], bf, acc);
      }
      *(f32x4*)(fpre_s + l16*132 + jq) = acc;
    }
    __syncthreads();
#pragma unroll
    for (int hf = 0; hf < 2; ++hf){
      const int ts = wv + 8*hf;
      float v0 = fpre_s[ts*132 + lane]      + pb0;
      float v1 = fpre_s[ts*132 + 64 + lane] + pb1;
      float s = v0 + v1, qq = v0*v0 + v1*v1;
      red2(s, qq);
      float mu = s * (1.0f/Hh);
      float rstd = rsqrtf(qq * (1.0f/Hh) - mu*mu + 1e-5f);
      float f0 = (v0 - mu)*rstd*gp0 + bp0;
      float f1 = (v1 - mu)*rstd*gp1 + bp1;
      f0 *= fast_rcp(1.0f + fast_ex2(-L2E*f0));
      f1 *= fast_rcp(1.0f + fast_ex2(-L2E*f1));
      feat_s[ts*136 + lane]      = (f16)f0;
      feat_s[ts*136 + 64 + lane] = (f16)f1;
    }
    __syncthreads();
    {
      half8 bf2[4];
#pragma unroll
      for (int c = 0; c < 4; ++c)
        bf2[c] = *(const half8*)(feat_s + l16*136 + 32*c + 8*q);
      const size_t trow = (size_t)(b*Tt + tl0 + l16) * 512;
      f32x4 accs2[4];
#pragma unroll
      for (int g = 0; g < 4; ++g){
        f32x4 acc = bias2[g];
#pragma unroll
        for (int c = 0; c < 4; ++c)
          acc = MFMA16(aW2[g][c], bf2[c], acc);
        accs2[g] = acc;
      }
      // scan layout store: j = 16wv+4q+r -> [w=wv>>1][l=4q+r][s=wv&1][g]
#pragma unroll
      for (int r = 0; r < 4; ++r){
        U2 u;
#pragma unroll
        for (int g = 0; g < 4; ++g) u.h[g] = (f16)accs2[g][r];
        const int zoff = ((wv>>1)*128) + ((4*q + r)*8) + ((wv&1)*4);
        *(uint2*)(zx + trow + zoff) = u.u;
      }
    }
    __syncthreads();
  }
}

// ---------------------------------------------------------------------------
// Scan v10 = verified v7 (2620us) + 2 safe deltas ONLY:
//  (1) lgkm-only barriers: chunk-stage global loads & h-dump stores fly
//      across step barriers (no per-step vmcnt(0) drain).
//  (2) zv software-pipeline: next step's z read (from stable zbuf[cur])
//      issues before this step's barrier, off the post-barrier critical path.
// Everything else byte-identical to v7.
// ---------------------------------------------------------------------------
__global__ __launch_bounds__(256, 1)
void scan_k(f16* __restrict__ zx, const float* __restrict__ dt,
            const float* __restrict__ w_ff1, const float* __restrict__ w_ff2,
            const float* __restrict__ w_ta,  const float* __restrict__ w_tb)
{
  __shared__ __align__(16) f16 zbuf[2][CH*512];  // 2 x 16 KB
  __shared__ __align__(16) f16 hist[CH][Hh];     // 4 KB ring of h

  const int tid  = threadIdx.x;
  const int wv   = tid >> 6;        // 0..3: j-range [32wv, 32wv+32)
  const int lane = tid & 63;
  const int q    = lane >> 4;
  const int l16  = lane & 15;
  const int sm   = q >> 1;          // this lane finalizes s = sm
  const int b    = blockIdx.x;

  const float* Wg[4] = { w_ff1, w_ff2, w_ta, w_tb };

  // B operand = W_bot (k rows 128..255), n = g*128 + 32wv + 16s + l16
  half8 bW[4][2][4];                // [gate][s][kchunk]
#pragma unroll
  for (int g = 0; g < 4; ++g){
    const float* wp = Wg[g];
#pragma unroll
    for (int s = 0; s < 2; ++s){
      const int jc = 32*wv + 16*s + l16;
#pragma unroll
      for (int c = 0; c < 4; ++c)
#pragma unroll
        for (int i = 0; i < 8; ++i)
          bW[g][s][c][i] = (f16)wp[(128 + 32*c + 8*q + i)*Hh + jc];
    }
  }

  // zero hist ring (slot 15 must be 0 for t=0)
  ((float4*)hist)[tid] = make_float4(0.f, 0.f, 0.f, 0.f);

  f16* zg = zx + (size_t)b*Tt*512;
  const float4* zg4 = (const float4*)zg;         // chunk = 1024 float4

  // prologue: chunk0 -> regs -> zbuf[0]; chunk1 -> regs; dt chunk0 -> reg
  float4 rz[4];
#pragma unroll
  for (int j = 0; j < 4; ++j) rz[j] = zg4[j*256 + tid];
#pragma unroll
  for (int j = 0; j < 4; ++j) ((float4*)zbuf[0])[j*256 + tid] = rz[j];
#pragma unroll
  for (int j = 0; j < 4; ++j) rz[j] = zg4[1024 + j*256 + tid];
  float dtcur = dt[(size_t)b*Tt + l16] * 10.0f;
  __syncthreads();

  const f32x4 zero4 = {0.f, 0.f, 0.f, 0.f};
  const int zlane = (wv*16 + l16)*8;             // lane's b128 slot in a step row

  for (int c = 0; c < NCH; ++c){
    const int cur = c & 1, nxt = cur ^ 1;
#pragma unroll
    for (int j = 0; j < 4; ++j) ((float4*)zbuf[nxt])[j*256 + tid] = rz[j];
    if (c + 2 < NCH){
      const float4* src = zg4 + (size_t)(c+2)*1024;
#pragma unroll
      for (int j = 0; j < 4; ++j) rz[j] = src[j*256 + tid];
    }
    float dtnxt = dtcur;
    if (c + 1 < NCH) dtnxt = dt[(size_t)b*Tt + (c+1)*CH + l16] * 10.0f;
    const f16* zch = zbuf[cur];

    // zv pipeline prologue: step-0 z (zbuf[cur] written LAST chunk, visible)
    half8 zv = *(const half8*)(zch + zlane);

#pragma unroll
    for (int st = 0; st < CH; ++st){
      const int slotR = (st + 15) & 15;
      // A operand: h broadcast (l16-independent), 4 x b128 — post-barrier path
      half8 af[4];
#pragma unroll
      for (int cc = 0; cc < 4; ++cc)
        af[cc] = *(const half8*)(&hist[slotR][32*cc + 8*q]);
      const half8 zvc = zv;
      const float dtt = rlane(dtcur, st);

      // 2+2 split K chains; only acc reg0 needed (M-rows duplicated)
      float R[4][2];
#pragma unroll
      for (int g = 0; g < 4; ++g)
#pragma unroll
        for (int s = 0; s < 2; ++s){
          f32x4 p = MFMA16(af[0], bW[g][s][0], zero4);
          p       = MFMA16(af[1], bW[g][s][1], p);
          f32x4 r2 = MFMA16(af[2], bW[g][s][2], zero4);
          r2       = MFMA16(af[3], bW[g][s][3], r2);
          R[g][s] = p[0] + r2[0];
        }
      // prefetch next step's z (zbuf[cur] stable within chunk) before barrier
      if (st + 1 < CH) zv = *(const half8*)(zch + (st+1)*512 + zlane);

      // own-s select + z add + CfC cell (one per lane)
      float pre[4];
#pragma unroll
      for (int g = 0; g < 4; ++g){
        float rv = sm ? R[g][1] : R[g][0];
        f16  zz = sm ? zvc[4+g] : zvc[g];
        pre[g] = rv + (float)zz;
      }
      // g_ has the longest dependent chain (fma -> exp2 -> add -> rcp): first.
      float gpre = __builtin_fmaf(pre[2], dtt, pre[3]);
      float g_ = fast_rcp(fast_ex2(-L2E*gpre) + 1.0f);
      float u_ = fast_rcp(fast_ex2(L2E2*pre[0]) + 1.0f);   // (1-tanh)/2
      float v_ = fast_rcp(fast_ex2(L2E2*pre[1]) + 1.0f);
      float a_ = __builtin_fmaf(-2.0f, u_, 1.0f);
      float hn = __builtin_fmaf(2.0f*g_, u_ - v_, a_);
      if ((q & 1) == 0)                          // q=0 -> s=0, q=2 -> s=1
        hist[st][32*wv + 16*sm + l16] = (f16)hn;
      SYNC();
    }
    // dump h ring into consumed z region: h[t] -> zg[t*512 + 0..127]
    {
      const float4 hv = ((const float4*)hist)[tid];
      *(float4*)(zg + ((size_t)(c*CH + (tid >> 4)))*512 + (size_t)(tid & 15)*8) = hv;
    }
    SYNC();
    dtcur = dtnxt;
  }
}

// ---------------------------------------------------------------------------
// Head: out[tok] = h[tok] . head_w + head_b (h fp16 from dumped region).
// ---------------------------------------------------------------------------
__global__ __launch_bounds__(256, 4)
void head_k(const f16* __restrict__ zx, const float* __restrict__ head_w,
            const float* __restrict__ head_b, float* __restrict__ out)
{
  const int tok  = (blockIdx.x << 2) + (threadIdx.x >> 6);
  const int lane = threadIdx.x & 63;
  U1 cv; cv.u = *(const unsigned*)(zx + (size_t)tok*512 + 2*lane);
  float s = (float)cv.h[0]*head_w[2*lane] + (float)cv.h[1]*head_w[2*lane+1];
#pragma unroll
  for (int off = 32; off; off >>= 1) s += __shfl_xor(s, off);
  if (lane == 0) out[tok] = s + head_b[0];
}

extern "C" void kernel_launch(void* const* d_in, const int* in_sizes, int n_in,
                              void* d_out, int out_size, void* d_ws, size_t ws_size,
                              hipStream_t stream)
{
  const float* x       = (const float*)d_in[0];
  const float* dt      = (const float*)d_in[1];
  const float* ln_in_g = (const float*)d_in[2];
  const float* ln_in_b = (const float*)d_in[3];
  const float* proj_w  = (const float*)d_in[4];
  const float* proj_b  = (const float*)d_in[5];
  const float* ln_p_g  = (const float*)d_in[6];
  const float* ln_p_b  = (const float*)d_in[7];
  const float* ff1_w   = (const float*)d_in[8];
  const float* ff1_b   = (const float*)d_in[9];
  const float* ff2_w   = (const float*)d_in[10];
  const float* ff2_b   = (const float*)d_in[11];
  const float* ta_w    = (const float*)d_in[12];
  const float* ta_b    = (const float*)d_in[13];
  const float* tb_w    = (const float*)d_in[14];
  const float* tb_b    = (const float*)d_in[15];
  const float* head_w  = (const float*)d_in[16];
  const float* head_b  = (const float*)d_in[17];

  f16*   zx  = (f16*)d_ws;      // [b][t][512] fp16 = 256 MiB (z, then h)
  float* out = (float*)d_out;

  stage_a<<<dim3(256), dim3(512), 0, stream>>>(
      x, ln_in_g, ln_in_b, proj_w, proj_b, ln_p_g, ln_p_b,
      ff1_w, ff1_b, ff2_w, ff2_b, ta_w, ta_b, tb_w, tb_b, zx);

  scan_k<<<dim3(Bb), dim3(256), 0, stream>>>(
      zx, dt, ff1_w, ff2_w, ta_w, tb_w);

  head_k<<<dim3(Bb*Tt/4), dim3(256), 0, stream>>>(
      zx, head_w, head_b, out);
}

// Round 6
// 2284.558 us; speedup vs baseline: 2.3804x; 1.2409x over previous
//
#include <hip/hip_runtime.h>
#include <cstdint>

#define Bb 64
#define Tt 4096
#define Dd 67
#define Hh 128
#define CH 16            // scan z-chunk: 16 steps x 512 n x 2B = 16 KB
#define NCH (Tt/CH)

typedef _Float16 f16;
typedef _Float16 half8 __attribute__((ext_vector_type(8)));
typedef float f32x4 __attribute__((ext_vector_type(4)));

#define MFMA16(A,B,C) __builtin_amdgcn_mfma_f32_16x16x32_f16((A),(B),(C),0,0,0)

static __device__ __forceinline__ float fast_rcp(float x){ return __builtin_amdgcn_rcpf(x); }
static __device__ __forceinline__ float fast_ex2(float x){ return __builtin_amdgcn_exp2f(x); }
static __device__ __forceinline__ float rlane(float v, int l){
  return __builtin_bit_cast(float, __builtin_amdgcn_readlane(__builtin_bit_cast(int, v), l));
}
#define L2E  1.442695041f
#define L2E2 2.885390082f

// LDS-visibility barrier WITHOUT vmcnt drain: global loads/stores stay in
// flight across it. "memory" clobber pins LDS op ordering at compile time;
// barrier builtin keeps convergence semantics.
#define SYNC() do { asm volatile("s_waitcnt lgkmcnt(0)" ::: "memory"); \
                    __builtin_amdgcn_s_barrier(); } while(0)

union U2 { uint2 u; f16 h[4]; };
union U1 { unsigned u; f16 h[2]; };

__device__ __forceinline__ void red2(float& s, float& q){
#pragma unroll
  for (int off = 32; off; off >>= 1){ s += __shfl_xor(s, off); q += __shfl_xor(q, off); }
}

// ---------------------------------------------------------------------------
// Stage A: LN(67) -> MFMA proj -> LN(128)+SiLU -> MFMA GEMM2 -> z fp16 to
// d_ws in scan layout [b][t][512], zoff(j,g)=(j>>5)*128+(j&15)*8+((j>>4)&1)*4+g.
// (unchanged, verified)
// ---------------------------------------------------------------------------
__global__ __launch_bounds__(512, 2)
void stage_a(const float* __restrict__ x,
             const float* __restrict__ g_in, const float* __restrict__ b_in,
             const float* __restrict__ proj_w, const float* __restrict__ proj_b,
             const float* __restrict__ g_p, const float* __restrict__ b_p,
             const float* __restrict__ w_ff1, const float* __restrict__ bi_ff1,
             const float* __restrict__ w_ff2, const float* __restrict__ bi_ff2,
             const float* __restrict__ w_ta,  const float* __restrict__ bi_ta,
             const float* __restrict__ w_tb,  const float* __restrict__ bi_tb,
             f16* __restrict__ zx)
{
  __shared__ __align__(16) f16   xn_s[16*104];
  __shared__ __align__(16) float fpre_s[16*132];
  __shared__ __align__(16) f16   feat_s[16*136];

  const int tid  = threadIdx.x;
  const int wv   = tid >> 6;
  const int lane = tid & 63;
  const int q    = lane >> 4;
  const int l16  = lane & 15;
  const int jq   = 16*wv + 4*q;

  const float* Wg[4] = { w_ff1, w_ff2, w_ta, w_tb };
  const float* Bg[4] = { bi_ff1, bi_ff2, bi_ta, bi_tb };

  half8 aW1[3];
#pragma unroll
  for (int c = 0; c < 3; ++c)
#pragma unroll
    for (int i = 0; i < 8; ++i){
      int k = 32*c + 8*q + i;
      aW1[c][i] = (k < Dd) ? (f16)proj_w[k*Hh + (16*wv + l16)] : (f16)0.f;
    }
  half8 aW2[4][4];
  f32x4 bias2[4];
#pragma unroll
  for (int g = 0; g < 4; ++g){
    const float* wp = Wg[g];
    const int jc = 16*wv + l16;
#pragma unroll
    for (int c = 0; c < 4; ++c)
#pragma unroll
      for (int i = 0; i < 8; ++i){
        int k = 32*c + 8*q + i;
        aW2[g][c][i] = (f16)wp[k*Hh + jc];
      }
    bias2[g] = *(const f32x4*)(Bg[g] + jq);
  }
  const float gi0 = g_in[lane], bi0 = b_in[lane];
  const float gi1 = (lane < 3) ? g_in[64+lane] : 0.f;
  const float bi1 = (lane < 3) ? b_in[64+lane] : 0.f;
  const float gp0 = g_p[lane],  bp0 = b_p[lane];
  const float gp1 = g_p[64+lane], bp1 = b_p[64+lane];
  const float pb0 = proj_b[lane], pb1 = proj_b[64+lane];

  for (int idx = tid; idx < 16*104; idx += 512)
    if ((idx % 104) >= Dd) xn_s[idx] = (f16)0.f;
  __syncthreads();

  const int wg   = blockIdx.x;
  const int b    = wg >> 2;
  const int t0wg = (wg & 3) * 1024;

  for (int it = 0; it < 64; ++it){
    const int tl0 = t0wg + it*16;
#pragma unroll
    for (int hf = 0; hf < 2; ++hf){
      const int ts = wv + 8*hf;
      const float* xr = x + (size_t)(b*Tt + tl0 + ts) * Dd;
      float v0 = xr[lane];
      float v1 = (lane < 3) ? xr[64+lane] : 0.f;
      float s = v0 + v1, qq = v0*v0 + v1*v1;
      red2(s, qq);
      float mu = s * (1.0f/Dd);
      float rstd = rsqrtf(qq * (1.0f/Dd) - mu*mu + 1e-5f);
      xn_s[ts*104 + lane] = (f16)((v0 - mu)*rstd*gi0 + bi0);
      if (lane < 3) xn_s[ts*104 + 64 + lane] = (f16)((v1 - mu)*rstd*gi1 + bi1);
    }
    __syncthreads();
    {
      f32x4 acc = {0.f, 0.f, 0.f, 0.f};
#pragma unroll
      for (int c = 0; c < 3; ++c){
        half8 bf = *(const half8*)(xn_s + l16*104 + 32*c + 8*q);
        acc = MFMA16(aW1[c], bf, acc);
      }
      *(f32x4*)(fpre_s + l16*132 + jq) = acc;
    }
    __syncthreads();
#pragma unroll
    for (int hf = 0; hf < 2; ++hf){
      const int ts = wv + 8*hf;
      float v0 = fpre_s[ts*132 + lane]      + pb0;
      float v1 = fpre_s[ts*132 + 64 + lane] + pb1;
      float s = v0 + v1, qq = v0*v0 + v1*v1;
      red2(s, qq);
      float mu = s * (1.0f/Hh);
      float rstd = rsqrtf(qq * (1.0f/Hh) - mu*mu + 1e-5f);
      float f0 = (v0 - mu)*rstd*gp0 + bp0;
      float f1 = (v1 - mu)*rstd*gp1 + bp1;
      f0 *= fast_rcp(1.0f + fast_ex2(-L2E*f0));
      f1 *= fast_rcp(1.0f + fast_ex2(-L2E*f1));
      feat_s[ts*136 + lane]      = (f16)f0;
      feat_s[ts*136 + 64 + lane] = (f16)f1;
    }
    __syncthreads();
    {
      half8 bf2[4];
#pragma unroll
      for (int c = 0; c < 4; ++c)
        bf2[c] = *(const half8*)(feat_s + l16*136 + 32*c + 8*q);
      const size_t trow = (size_t)(b*Tt + tl0 + l16) * 512;
      f32x4 accs2[4];
#pragma unroll
      for (int g = 0; g < 4; ++g){
        f32x4 acc = bias2[g];
#pragma unroll
        for (int c = 0; c < 4; ++c)
          acc = MFMA16(aW2[g][c], bf2[c], acc);
        accs2[g] = acc;
      }
      // scan layout store: j = 16wv+4q+r -> [w=wv>>1][l=4q+r][s=wv&1][g]
#pragma unroll
      for (int r = 0; r < 4; ++r){
        U2 u;
#pragma unroll
        for (int g = 0; g < 4; ++g) u.h[g] = (f16)accs2[g][r];
        const int zoff = ((wv>>1)*128) + ((4*q + r)*8) + ((wv&1)*4);
        *(uint2*)(zx + trow + zoff) = u.u;
      }
    }
    __syncthreads();
  }
}

// ---------------------------------------------------------------------------
// Scan v11 = v10 wins (lgkm-only SYNC, zv prefetch, chunked staging) at
// 8 waves/block (512 thr): wave w8 owns j = 16*w8 + l16 -> 16 MFMA/wave
// (8 indep depth-2 chains), NO s-duplication (64 weight VGPRs). 2 waves/SIMD
// overlap af-read latency, MFMA issue gaps, and cell VALU across waves.
// Lane (q,l16): all q compute cell for j (redundant), q==0 writes hist.
// z read = 1 uint2/lane from stage_a's layout (w8>>1, l16, w8&1 index match).
// ---------------------------------------------------------------------------
__global__ __launch_bounds__(512, 1)
void scan_k(f16* __restrict__ zx, const float* __restrict__ dt,
            const float* __restrict__ w_ff1, const float* __restrict__ w_ff2,
            const float* __restrict__ w_ta,  const float* __restrict__ w_tb)
{
  __shared__ __align__(16) f16 zbuf[2][CH*512];  // 2 x 16 KB
  __shared__ __align__(16) f16 hist[CH][Hh];     // 4 KB ring of h [16][128]

  const int tid  = threadIdx.x;
  const int w8   = tid >> 6;        // 0..7: j-range [16*w8, 16*w8+16)
  const int lane = tid & 63;
  const int q    = lane >> 4;
  const int l16  = lane & 15;
  const int b    = blockIdx.x;

  const float* Wg[4] = { w_ff1, w_ff2, w_ta, w_tb };

  // B operand = W_bot (k rows 128..255), col jc = 16*w8 + l16
  half8 bW[4][4];                   // [gate][kchunk]
#pragma unroll
  for (int g = 0; g < 4; ++g){
    const float* wp = Wg[g];
    const int jc = 16*w8 + l16;
#pragma unroll
    for (int c = 0; c < 4; ++c)
#pragma unroll
      for (int i = 0; i < 8; ++i)
        bW[g][c][i] = (f16)wp[(128 + 32*c + 8*q + i)*Hh + jc];
  }

  // zero hist ring (slot 15 must be 0 for t=0): 512 thr x 8B = 4 KB
  ((float2*)hist)[tid] = make_float2(0.f, 0.f);

  f16* zg = zx + (size_t)b*Tt*512;
  const float4* zg4 = (const float4*)zg;         // chunk = 1024 float4

  // prologue: chunk0 -> regs -> zbuf[0]; chunk1 -> regs; dt chunk0 -> reg
  float4 rz[2];
  rz[0] = zg4[tid]; rz[1] = zg4[512 + tid];
  ((float4*)zbuf[0])[tid] = rz[0]; ((float4*)zbuf[0])[512 + tid] = rz[1];
  rz[0] = zg4[1024 + tid]; rz[1] = zg4[1536 + tid];
  float dtcur = dt[(size_t)b*Tt + l16] * 10.0f;
  __syncthreads();

  const f32x4 zero4 = {0.f, 0.f, 0.f, 0.f};
  // lane's z slot (f16 elems) in a step row: j=16w8+l16 ->
  // (j>>5)*128 + (j&15)*8 + ((j>>4)&1)*4  (+g)
  const int zoff2 = (w8>>1)*128 + l16*8 + (w8&1)*4;

  for (int c = 0; c < NCH; ++c){
    const int cur = c & 1, nxt = cur ^ 1;
    ((float4*)zbuf[nxt])[tid] = rz[0];
    ((float4*)zbuf[nxt])[512 + tid] = rz[1];
    if (c + 2 < NCH){
      const float4* src = zg4 + (size_t)(c+2)*1024;
      rz[0] = src[tid]; rz[1] = src[512 + tid];
    }
    float dtnxt = dtcur;
    if (c + 1 < NCH) dtnxt = dt[(size_t)b*Tt + (c+1)*CH + l16] * 10.0f;
    const f16* zch = zbuf[cur];

    // zv pipeline prologue: step-0 z (zbuf[cur] written LAST chunk, visible)
    uint2 zv = *(const uint2*)(zch + zoff2);

#pragma unroll
    for (int st = 0; st < CH; ++st){
      const int slotR = (st + 15) & 15;
      // A operand: h broadcast (l16-independent), 4 x b128 — post-barrier path
      half8 af[4];
#pragma unroll
      for (int cc = 0; cc < 4; ++cc)
        af[cc] = *(const half8*)(&hist[slotR][32*cc + 8*q]);
      U2 uz; uz.u = zv;
      const float dtt = rlane(dtcur, st);

      // 8 indep depth-2 chains (4 gates x 2+2 K-split), 16 MFMA/wave
      f32x4 pA[4], pB[4];
#pragma unroll
      for (int g = 0; g < 4; ++g) pA[g] = MFMA16(af[0], bW[g][0], zero4);
#pragma unroll
      for (int g = 0; g < 4; ++g) pB[g] = MFMA16(af[2], bW[g][2], zero4);
#pragma unroll
      for (int g = 0; g < 4; ++g) pA[g] = MFMA16(af[1], bW[g][1], pA[g]);
#pragma unroll
      for (int g = 0; g < 4; ++g) pB[g] = MFMA16(af[3], bW[g][3], pB[g]);

      // prefetch next step's z (zbuf[cur] stable within chunk) before barrier
      if (st + 1 < CH) zv = *(const uint2*)(zch + (st+1)*512 + zoff2);

      // cell for j = 16w8+l16 (q-redundant; q==0 writes)
      float pre[4];
#pragma unroll
      for (int g = 0; g < 4; ++g)
        pre[g] = pA[g][0] + pB[g][0] + (float)uz.h[g];
      float gpre = __builtin_fmaf(pre[2], dtt, pre[3]);
      float g_ = fast_rcp(fast_ex2(-L2E*gpre) + 1.0f);
      float u_ = fast_rcp(fast_ex2(L2E2*pre[0]) + 1.0f);   // (1-tanh)/2
      float v_ = fast_rcp(fast_ex2(L2E2*pre[1]) + 1.0f);
      float a_ = __builtin_fmaf(-2.0f, u_, 1.0f);
      float hn = __builtin_fmaf(2.0f*g_, u_ - v_, a_);
      if (q == 0)
        hist[st][16*w8 + l16] = (f16)hn;
      SYNC();
    }
    // dump h ring into consumed z region: h[t] -> zg[t*512 + 0..127]
    {
      const uint2 hv = ((const uint2*)hist)[tid];
      *(uint2*)(zg + ((size_t)(c*CH + (tid >> 5)))*512 + (size_t)(tid & 31)*4) = hv;
    }
    SYNC();
    dtcur = dtnxt;
  }
}

// ---------------------------------------------------------------------------
// Head: out[tok] = h[tok] . head_w + head_b (h fp16 from dumped region).
// ---------------------------------------------------------------------------
__global__ __launch_bounds__(256, 4)
void head_k(const f16* __restrict__ zx, const float* __restrict__ head_w,
            const float* __restrict__ head_b, float* __restrict__ out)
{
  const int tok  = (blockIdx.x << 2) + (threadIdx.x >> 6);
  const int lane = threadIdx.x & 63;
  U1 cv; cv.u = *(const unsigned*)(zx + (size_t)tok*512 + 2*lane);
  float s = (float)cv.h[0]*head_w[2*lane] + (float)cv.h[1]*head_w[2*lane+1];
#pragma unroll
  for (int off = 32; off; off >>= 1) s += __shfl_xor(s, off);
  if (lane == 0) out[tok] = s + head_b[0];
}

extern "C" void kernel_launch(void* const* d_in, const int* in_sizes, int n_in,
                              void* d_out, int out_size, void* d_ws, size_t ws_size,
                              hipStream_t stream)
{
  const float* x       = (const float*)d_in[0];
  const float* dt      = (const float*)d_in[1];
  const float* ln_in_g = (const float*)d_in[2];
  const float* ln_in_b = (const float*)d_in[3];
  const float* proj_w  = (const float*)d_in[4];
  const float* proj_b  = (const float*)d_in[5];
  const float* ln_p_g  = (const float*)d_in[6];
  const float* ln_p_b  = (const float*)d_in[7];
  const float* ff1_w   = (const float*)d_in[8];
  const float* ff1_b   = (const float*)d_in[9];
  const float* ff2_w   = (const float*)d_in[10];
  const float* ff2_b   = (const float*)d_in[11];
  const float* ta_w    = (const float*)d_in[12];
  const float* ta_b    = (const float*)d_in[13];
  const float* tb_w    = (const float*)d_in[14];
  const float* tb_b    = (const float*)d_in[15];
  const float* head_w  = (const float*)d_in[16];
  const float* head_b  = (const float*)d_in[17];

  f16*   zx  = (f16*)d_ws;      // [b][t][512] fp16 = 256 MiB (z, then h)
  float* out = (float*)d_out;

  stage_a<<<dim3(256), dim3(512), 0, stream>>>(
      x, ln_in_g, ln_in_b, proj_w, proj_b, ln_p_g, ln_p_b,
      ff1_w, ff1_b, ff2_w, ff2_b, ta_w, ta_b, tb_w, tb_b, zx);

  scan_k<<<dim3(Bb), dim3(512), 0, stream>>>(
      zx, dt, ff1_w, ff2_w, ta_w, tb_w);

  head_k<<<dim3(Bb*Tt/4), dim3(256), 0, stream>>>(
      zx, head_w, head_b, out);
}